// Round 7
// baseline (71.539 us; speedup 1.0000x reference)
//
#include <hip/hip_runtime.h>
#include <math.h>

namespace {
constexpr int N_ = 2048;
constexpr int D_ = 128;
constexpr int K_ = 8;
constexpr int M_ = 64;
constexpr float JIT = 1e-5f;
constexpr float L2E = 1.4426950408889634f;
constexpr float LN2 = 0.6931471805599453f;

// ws layout (float offsets)
constexpr int OFF_ARR2 = 0;                 // N*16 : per-n [a[8], ib2s[8]]
constexpr int OFF_C2   = 32768;             // N    : prod rsqrt(2s2+1)
constexpr int OFF_ARR1 = 34816;             // N*16 : per-n [a[8], ib1s[8]]
constexpr int OFF_CY   = 67584;             // N    : prod rsqrt(1+s2) * Y[n]
constexpr int OFF_P2P  = 69632;             // 8*4096 : psi2 partial sums
constexpr int OFF_P1Y  = 102400;            // 8*64   : Psi1^T Y partials
constexpr int OFF_KUI  = 102912;            // 4096   : -Kuu^{-1} row-major
constexpr int OFF_SC   = 107008;            // 3      : YY, KL, log2det terms
}

struct F8 { float f[8]; };

__device__ __forceinline__ float f4e(float4 v, int e) {
  return (e == 0) ? v.x : (e == 1) ? v.y : (e == 2) ? v.z : v.w;
}

// unrolled 2x2-block symmetric sweep: reg (column `lane` of SPD A) ->
// column of (-A^{-1}); returns log2(det A). rowbuf is [parity*2 + A/B][64].
__device__ __forceinline__ float sweep2x2(float* reg, float (*rowbuf)[M_], int lane) {
  float ld = 0.f;
#pragma unroll
  for (int p = 0; p < M_; p += 2) {
    const int par = (p >> 1) & 1;
    float* rbA = rowbuf[par * 2 + 0];
    float* rbB = rowbuf[par * 2 + 1];
    rbA[lane] = reg[p];
    rbB[lane] = reg[p + 1];
    float4 ra[16], rb[16];
    const float4* rbAq = reinterpret_cast<const float4*>(rbA);
    const float4* rbBq = reinterpret_cast<const float4*>(rbB);
#pragma unroll
    for (int q = 0; q < 16; q++) { ra[q] = rbAq[q]; rb[q] = rbBq[q]; }

    const float P00 = f4e(ra[p >> 2], p & 3);
    const float P01 = f4e(ra[(p + 1) >> 2], (p + 1) & 3);
    const float P11 = f4e(rb[(p + 1) >> 2], (p + 1) & 3);
    const float det = fmaf(P00, P11, -P01 * P01);
    const float idet = __builtin_amdgcn_rcpf(det);
    ld += __log2f(det);
    const float Pi00 =  P11 * idet;
    const float Pi01 = -P01 * idet;
    const float Pi11 =  P00 * idet;

    const bool isp = (lane == p), isq = (lane == p + 1);
    const float a0 = reg[p], a1 = reg[p + 1];
    const float w0 = isp ? Pi00 : (isq ? Pi01 : fmaf(Pi00, a0, Pi01 * a1));
    const float w1 = isp ? Pi01 : (isq ? Pi11 : fmaf(Pi01, a0, Pi11 * a1));
    const float t0 = isp ? (1.f - w0) : (isq ? -w0 : w0);
    const float t1 = isq ? (1.f - w1) : (isp ? -w1 : w1);
    const float f0 = (isp || isq) ? -w0 : w0;
    const float f1 = (isp || isq) ? -w1 : w1;
#pragma unroll
    for (int q = 0; q < 16; q++) {
      const float4 va = ra[q], vb = rb[q];
      reg[4 * q + 0] = fmaf(-t1, vb.x, fmaf(-t0, va.x, reg[4 * q + 0]));
      reg[4 * q + 1] = fmaf(-t1, vb.y, fmaf(-t0, va.y, reg[4 * q + 1]));
      reg[4 * q + 2] = fmaf(-t1, vb.z, fmaf(-t0, va.z, reg[4 * q + 2]));
      reg[4 * q + 3] = fmaf(-t1, vb.w, fmaf(-t0, va.w, reg[4 * q + 3]));
    }
    reg[p] = f0;
    reg[p + 1] = f1;
  }
  return ld;
}

// ---------------------------------------------------------------------------
// K1: 9 blocks. b<8: prep (per-n stats -> ws). b==8: Kuu^{-1} sweep + YY + KL.
// ---------------------------------------------------------------------------
__global__ __launch_bounds__(256) void vdmgp_k1(
    const float* __restrict__ X, const float* __restrict__ Y,
    const float* __restrict__ qmu, const float* __restrict__ qcov,
    const float* __restrict__ Z, float* __restrict__ ws) {
  __shared__ float smu[D_ * K_];   // [d][k]
  __shared__ float scov[D_ * K_];
  __shared__ float zl[M_][9];
  __shared__ __align__(16) float rowbuf[4][M_];

  const int tid = threadIdx.x;
  const int b = blockIdx.x;

  if (b == 8) {
    for (int idx = tid; idx < M_ * K_; idx += 256) zl[idx >> 3][idx & 7] = Z[idx];
    __syncthreads();
    const int lane = tid & 63;
    const int wave = tid >> 6;
    if (wave == 0) {
      float zj[K_];
#pragma unroll
      for (int k = 0; k < K_; k++) zj[k] = zl[lane][k];
      float reg[M_];
#pragma unroll
      for (int i = 0; i < M_; i++) {
        float sq = 0.f;
#pragma unroll
        for (int k = 0; k < K_; k++) { const float dd = zl[i][k] - zj[k]; sq = fmaf(dd, dd, sq); }
        reg[i] = exp2f(-0.5f * L2E * sq) + ((i == lane) ? JIT : 0.f);
      }
      const float ld = sweep2x2(reg, rowbuf, lane);
#pragma unroll
      for (int i = 0; i < M_; i++) ws[OFF_KUI + i * 64 + lane] = reg[i];
      if (lane == 0) ws[OFF_SC + 2] = LN2 * ld;
    } else if (wave == 1) {
      float yy = 0.f;
#pragma unroll
      for (int t = 0; t < 32; t++) {
        const float y = Y[t * 64 + lane];
        yy = fmaf(y, y, yy);
      }
#pragma unroll
      for (int off = 32; off > 0; off >>= 1) yy += __shfl_down(yy, off, 64);
      if (lane == 0) ws[OFF_SC + 0] = yy;
    } else if (wave == 2) {
      const int k = lane >> 3;
      const int d0 = (lane & 7) * 16;
      float slog = 0.f, srow = 0.f;
#pragma unroll
      for (int t = 0; t < 16; t++) {
        const float qc = qcov[k * D_ + d0 + t];
        const float qm = qmu[k * D_ + d0 + t];
        slog += logf(qc);
        srow += qc + qm * qm;
      }
#pragma unroll
      for (int off = 4; off > 0; off >>= 1) {
        slog += __shfl_down(slog, off, 8);
        srow += __shfl_down(srow, off, 8);
      }
      float klr = ((lane & 7) == 0)
          ? (slog - (float)D_ * logf(srow) + (float)D_ * logf((float)D_)) : 0.f;
      klr += __shfl_down(klr, 32, 64);
      klr += __shfl_down(klr, 16, 64);
      klr += __shfl_down(klr, 8, 64);
      if (lane == 0) ws[OFF_SC + 1] = klr;
    }
    return;
  }

  // prep: one n per thread
  for (int idx = tid; idx < K_ * D_; idx += 256) {
    int k = idx >> 7, d = idx & 127;
    smu[d * K_ + k]  = qmu[idx];
    scov[d * K_ + k] = qcov[idx];
  }
  __syncthreads();

  const int n = b * 256 + tid;
  float a[K_], s2[K_];
#pragma unroll
  for (int k = 0; k < K_; k++) { a[k] = 0.f; s2[k] = 0.f; }

  const float4* xrow = reinterpret_cast<const float4*>(X + n * D_);
#pragma unroll 2
  for (int dq = 0; dq < D_ / 4; dq++) {
    float4 xv = xrow[dq];
    float xs[4] = {xv.x, xv.y, xv.z, xv.w};
#pragma unroll
    for (int t = 0; t < 4; t++) {
      const int d = dq * 4 + t;
      const float x = xs[t];
      const float xx = x * x;
      F8 mu = *reinterpret_cast<const F8*>(&smu[d * K_]);
      F8 cv = *reinterpret_cast<const F8*>(&scov[d * K_]);
#pragma unroll
      for (int k = 0; k < K_; k++) {
        a[k]  = fmaf(mu.f[k], x, a[k]);
        s2[k] = fmaf(cv.f[k], xx, s2[k]);
      }
    }
  }

  float4 w2[4], w1[4];
  float prod2 = 1.f, prod1 = 1.f;
#pragma unroll
  for (int k = 0; k < K_; k++) {
    const float b2 = 2.f * s2[k] + 1.f;
    const float b1 = 1.f + s2[k];
    reinterpret_cast<float*>(w2)[k]     = a[k];
    reinterpret_cast<float*>(w2)[8 + k] = L2E / b2;
    reinterpret_cast<float*>(w1)[k]     = a[k];
    reinterpret_cast<float*>(w1)[8 + k] = 0.5f * L2E / b1;
    prod2 *= rsqrtf(b2);
    prod1 *= rsqrtf(b1);
  }
  float4* a2q = reinterpret_cast<float4*>(ws + OFF_ARR2 + n * 16);
  float4* a1q = reinterpret_cast<float4*>(ws + OFF_ARR1 + n * 16);
#pragma unroll
  for (int e = 0; e < 4; e++) { a2q[e] = w2[e]; a1q[e] = w1[e]; }
  (ws + OFF_C2)[n] = prod2;
  (ws + OFF_CY)[n] = prod1 * Y[n];
}

// ---------------------------------------------------------------------------
// K2: grid (16, 9). by<8: psi2 chunk (256 n). by==8 && bx<8: Psi1^T Y chunk.
// Inner loops unrolled x4 with batched LDS loads.
// ---------------------------------------------------------------------------
__global__ __launch_bounds__(256) void vdmgp_k2(
    const float* __restrict__ Z, float* __restrict__ ws) {
  __shared__ float sa[256 * 16];
  __shared__ float sc[256];
  __shared__ float red[256];
  const int tid = threadIdx.x;
  const int bx = blockIdx.x, by = blockIdx.y;

  if (by < 8) {
    // psi2 chunk: 256 n
    const int nbase = by * 256;
    {
      const float4* src = reinterpret_cast<const float4*>(ws + OFF_ARR2 + nbase * 16);
      float4* dst = reinterpret_cast<float4*>(sa);
#pragma unroll
      for (int r = 0; r < 4; r++) dst[r * 256 + tid] = src[r * 256 + tid];
      sc[tid] = (ws + OFF_C2)[nbase + tid];
    }
    __syncthreads();

    const int pair = bx * 256 + tid;
    const int i = pair >> 6, j = pair & 63;
    float zb[K_];
#pragma unroll
    for (int k = 0; k < K_; k++) zb[k] = 0.5f * (Z[i * K_ + k] + Z[j * K_ + k]);

    float acc = 0.f;
    for (int nl = 0; nl < 256; nl += 4) {
      F8 av0 = *reinterpret_cast<const F8*>(&sa[(nl + 0) * 16]);
      F8 ib0 = *reinterpret_cast<const F8*>(&sa[(nl + 0) * 16 + 8]);
      F8 av1 = *reinterpret_cast<const F8*>(&sa[(nl + 1) * 16]);
      F8 ib1 = *reinterpret_cast<const F8*>(&sa[(nl + 1) * 16 + 8]);
      F8 av2 = *reinterpret_cast<const F8*>(&sa[(nl + 2) * 16]);
      F8 ib2 = *reinterpret_cast<const F8*>(&sa[(nl + 2) * 16 + 8]);
      F8 av3 = *reinterpret_cast<const F8*>(&sa[(nl + 3) * 16]);
      F8 ib3 = *reinterpret_cast<const F8*>(&sa[(nl + 3) * 16 + 8]);
      float s0 = 0.f, s1 = 0.f, s2 = 0.f, s3 = 0.f;
#pragma unroll
      for (int k = 0; k < K_; k++) {
        const float t0 = av0.f[k] - zb[k]; s0 = fmaf(t0 * t0, ib0.f[k], s0);
        const float t1 = av1.f[k] - zb[k]; s1 = fmaf(t1 * t1, ib1.f[k], s1);
        const float t2 = av2.f[k] - zb[k]; s2 = fmaf(t2 * t2, ib2.f[k], s2);
        const float t3 = av3.f[k] - zb[k]; s3 = fmaf(t3 * t3, ib3.f[k], s3);
      }
      acc = fmaf(sc[nl + 0], exp2f(-s0), acc);
      acc = fmaf(sc[nl + 1], exp2f(-s1), acc);
      acc = fmaf(sc[nl + 2], exp2f(-s2), acc);
      acc = fmaf(sc[nl + 3], exp2f(-s3), acc);
    }
    (ws + OFF_P2P)[by * 4096 + pair] = acc;
    return;
  }

  // by == 8: Psi1^T Y chunk bx — ONLY bx<8 are valid (8 chunks of 256 n).
  // bx>=8 must exit: running them would read OOB stats AND overwrite OFF_KUI.
  if (bx >= 8) return;
  {
    const int nbase = bx * 256;
    const float4* src = reinterpret_cast<const float4*>(ws + OFF_ARR1 + nbase * 16);
    float4* dst = reinterpret_cast<float4*>(sa);
#pragma unroll
    for (int r = 0; r < 4; r++) dst[r * 256 + tid] = src[r * 256 + tid];
    sc[tid] = (ws + OFF_CY)[nbase + tid];
    __syncthreads();

    const int m = tid & 63;
    const int stripe = tid >> 6;
    float zm[K_];
#pragma unroll
    for (int k = 0; k < K_; k++) zm[k] = Z[m * K_ + k];

    float acc = 0.f;
    for (int t = 0; t < 64; t += 4) {
      const int nl = stripe * 64 + t;
      F8 av0 = *reinterpret_cast<const F8*>(&sa[(nl + 0) * 16]);
      F8 ib0 = *reinterpret_cast<const F8*>(&sa[(nl + 0) * 16 + 8]);
      F8 av1 = *reinterpret_cast<const F8*>(&sa[(nl + 1) * 16]);
      F8 ib1 = *reinterpret_cast<const F8*>(&sa[(nl + 1) * 16 + 8]);
      F8 av2 = *reinterpret_cast<const F8*>(&sa[(nl + 2) * 16]);
      F8 ib2 = *reinterpret_cast<const F8*>(&sa[(nl + 2) * 16 + 8]);
      F8 av3 = *reinterpret_cast<const F8*>(&sa[(nl + 3) * 16]);
      F8 ib3 = *reinterpret_cast<const F8*>(&sa[(nl + 3) * 16 + 8]);
      float s0 = 0.f, s1 = 0.f, s2 = 0.f, s3 = 0.f;
#pragma unroll
      for (int k = 0; k < K_; k++) {
        const float d0 = av0.f[k] - zm[k]; s0 = fmaf(d0 * d0, ib0.f[k], s0);
        const float d1 = av1.f[k] - zm[k]; s1 = fmaf(d1 * d1, ib1.f[k], s1);
        const float d2 = av2.f[k] - zm[k]; s2 = fmaf(d2 * d2, ib2.f[k], s2);
        const float d3 = av3.f[k] - zm[k]; s3 = fmaf(d3 * d3, ib3.f[k], s3);
      }
      acc = fmaf(sc[nl + 0], exp2f(-s0), acc);
      acc = fmaf(sc[nl + 1], exp2f(-s1), acc);
      acc = fmaf(sc[nl + 2], exp2f(-s2), acc);
      acc = fmaf(sc[nl + 3], exp2f(-s3), acc);
    }
    red[tid] = acc;
    __syncthreads();
    if (tid < 64)
      (ws + OFF_P1Y)[bx * 64 + tid] =
          red[tid] + red[64 + tid] + red[128 + tid] + red[192 + tid];
  }
}

// ---------------------------------------------------------------------------
// K3: 1 block. reduce psi2 partials (fold left) + pys; wave0: KuPsi2 sweep;
// wave1: trace vs precomputed -Kuu^{-1}; combine.
// ---------------------------------------------------------------------------
__global__ __launch_bounds__(256, 1) void vdmgp_k3(
    const float* __restrict__ Z,
    const float* __restrict__ sfp, const float* __restrict__ nvp,
    const float* __restrict__ ws, float* __restrict__ out) {
  __shared__ float P2s[M_][M_];
  __shared__ float zl[M_][9];
  __shared__ float pysL[M_];
  __shared__ __align__(16) float rowbuf[4][M_];
  __shared__ float scal[8];

  const int tid = threadIdx.x;
  const int lane = tid & 63;
  const int wave = tid >> 6;
  const float sf = sfp[0];
  const float s2v = nvp[0];

  for (int idx = tid; idx < M_ * K_; idx += 256) zl[idx >> 3][idx & 7] = Z[idx];
  if (tid < M_) {
    const float* p1y = ws + OFF_P1Y;
    float s = 0.f;
#pragma unroll
    for (int c = 0; c < 8; c++) s += p1y[c * M_ + tid];
    pysL[tid] = sf * s;
  }
  __syncthreads();

  // reduce the 8 psi2 partial chunks, fold `left`
  const float4* part4 = reinterpret_cast<const float4*>(ws + OFF_P2P);
  const float sf2 = sf * sf;
#pragma unroll
  for (int g = 0; g < 4; g++) {
    const int idx4 = g * 256 + tid;
    float4 acc = {0.f, 0.f, 0.f, 0.f};
#pragma unroll
    for (int c = 0; c < 8; c++) {
      const float4 v = part4[c * 1024 + idx4];
      acc.x += v.x; acc.y += v.y; acc.z += v.z; acc.w += v.w;
    }
    const int i = idx4 >> 4;
    const int j0 = (idx4 & 15) * 4;
    float o[4];
#pragma unroll
    for (int e = 0; e < 4; e++) {
      const int j = j0 + e;
      float sq = 0.f;
#pragma unroll
      for (int k = 0; k < K_; k++) {
        const float dd = zl[i][k] - zl[j][k];
        sq = fmaf(dd, dd, sq);
      }
      o[e] = sf2 * exp2f(-0.25f * L2E * sq) * f4e(acc, e);
    }
    *reinterpret_cast<float4*>(&P2s[i][j0]) = make_float4(o[0], o[1], o[2], o[3]);
  }
  __syncthreads();

  if (wave == 0) {
    float zj[K_];
#pragma unroll
    for (int k = 0; k < K_; k++) zj[k] = zl[lane][k];
    float reg[M_];
#pragma unroll
    for (int i = 0; i < M_; i++) {
      float sq = 0.f;
#pragma unroll
      for (int k = 0; k < K_; k++) { const float dd = zl[i][k] - zj[k]; sq = fmaf(dd, dd, sq); }
      const float jit = (i == lane) ? JIT : 0.f;
      const float kj = exp2f(-0.5f * L2E * sq) + jit;
      reg[i] = fmaf(s2v, kj, P2s[i][lane] + jit);
    }
    const float ld2 = sweep2x2(reg, rowbuf, lane);
    float local = 0.f;
#pragma unroll
    for (int i = 0; i < M_; i++) local = fmaf(reg[i], pysL[i], local);
    local *= pysL[lane];
#pragma unroll
    for (int off = 32; off > 0; off >>= 1) local += __shfl_down(local, off, 64);
    if (lane == 0) {
      scal[6] = LN2 * ld2;
      scal[7] = -local;     // quad
    }
  } else if (wave == 1) {
    const float* kui = ws + OFF_KUI;   // holds -Kuu^{-1}
    float acc = 0.f;
#pragma unroll
    for (int i = 0; i < M_; i++) acc = fmaf(kui[i * 64 + lane], P2s[i][lane], acc);
#pragma unroll
    for (int off = 32; off > 0; off >>= 1) acc += __shfl_down(acc, off, 64);
    if (lane == 0) scal[5] = -acc;     // trace
  }
  __syncthreads();

  if (tid == 0) {
    const float YY  = ws[OFF_SC + 0];
    const float KL  = ws[OFF_SC + 1];
    const float ld1 = ws[OFF_SC + 2];
    const float tr = scal[5], ld2 = scal[6], quad = scal[7];
    const float inv = 1.0f / s2v;
    const float F1 = -(float)N_ * 1.8378770664093453f      // N*log(2*pi)
                   - (float)(N_ - M_) * logf(s2v)
                   + (ld1 - ld2)
                   - YY * inv
                   + quad * inv
                   - (float)N_ * sf * sf * inv
                   + tr * inv;
    out[0] = 0.5f * (F1 + KL);
  }
}

extern "C" void kernel_launch(void* const* d_in, const int* in_sizes, int n_in,
                              void* d_out, int out_size, void* d_ws, size_t ws_size,
                              hipStream_t stream) {
  const float* X    = (const float*)d_in[0];
  const float* Y    = (const float*)d_in[1];
  const float* qmu  = (const float*)d_in[2];
  const float* qcov = (const float*)d_in[3];
  const float* Z    = (const float*)d_in[4];
  const float* sfp  = (const float*)d_in[5];
  const float* nvp  = (const float*)d_in[6];
  float* ws  = (float*)d_ws;
  float* out = (float*)d_out;

  vdmgp_k1<<<9, 256, 0, stream>>>(X, Y, qmu, qcov, Z, ws);
  vdmgp_k2<<<dim3(16, 9), 256, 0, stream>>>(Z, ws);
  vdmgp_k3<<<1, 256, 0, stream>>>(Z, sfp, nvp, ws, out);
}